// Round 4
// baseline (204.596 us; speedup 1.0000x reference)
//
#include <hip/hip_runtime.h>

// out[r] = sum_{s in ray r} w[s] * rgb[s,:]  (segment_ids sorted, fp32)
// Wave-autonomous, barrier-free.
// v5: atomic-free steady-state loop. v4 post-mortem: with in-order vmcnt
// retirement (m135), the per-chunk atomics sat OLDER than the awaited stage
// batch -> every vmcnt(5) forced a full device-scope atomic round trip; plus
// lockstep waves convoy -> load-issue duty cycle ~40%. Fix:
//   1) cross-chunk carry: lane 63's post-scan tail partial is broadcast and
//      seeded into the next chunk's first run (runs usually continue across
//      chunks; avg run = 64 samples = 1 chunk/4) -> no per-chunk tail flush
//   2) deferred flush: run-end triplets buffered in 2 register slots/lane
//      (overflow -> immediate atomic, ~1% of lanes); all atomics emitted
//      after the last chunk -> the 8-chunk main loop is loads+VALU/DS only
//   3) vmcnt(5) window now contains exactly the next chunk's 5 stage ops
//   - geometry identical to v4: 2048 samples/wave, 8 chunks x 256, 2 LDS
//     buffers x 5 KB/wave, 40 KB/block, 4 blocks/CU, grid = exactly resident

#define NTHREADS 256
#define WAVES_PER_BLOCK (NTHREADS / 64)
#define CPL 4                      // samples per lane per chunk
#define CHUNK (64 * CPL)           // 256 samples
#define CHUNKS 8                   // chunks per wave span
#define SPW (CHUNK * CHUNKS)       // 2048 samples per wave
#define CHUNK_BYTES (CHUNK * 20)   // 5120 B: ids 1K | w 1K | rgb 3K
#define IDS_OFF 0
#define W_OFF 1024
#define RGB_OFF 2048

__device__ __forceinline__ void gll16(const void* g, void* l) {
  // moves 64 lanes x 16 B; LDS dest = wave-uniform base + lane*16
  __builtin_amdgcn_global_load_lds(
      (const __attribute__((address_space(1))) void*)g,
      (__attribute__((address_space(3))) void*)l, 16, 0, 0);
}

// Immediate-flush variant used only on the bounds-checked tail path.
__device__ __forceinline__ void process_chunk_tailpath(
    const int4 id4, const float4 w4, const float4 r0, const float4 r1,
    const float4 r2, const int lane, float* __restrict__ out) {
  int idv[CPL] = {id4.x, id4.y, id4.z, id4.w};
  float px[CPL], py[CPL], pz[CPL];
  px[0] = r0.x * w4.x; py[0] = r0.y * w4.x; pz[0] = r0.z * w4.x;
  px[1] = r0.w * w4.y; py[1] = r1.x * w4.y; pz[1] = r1.y * w4.y;
  px[2] = r1.z * w4.z; py[2] = r1.w * w4.z; pz[2] = r2.x * w4.z;
  px[3] = r2.y * w4.w; py[3] = r2.z * w4.w; pz[3] = r2.w * w4.w;

  const int first_id = idv[0];
  int run_id = first_id;
  float rx = px[0], ry = py[0], rz = pz[0];
  float hx = 0.f, hy = 0.f, hz = 0.f;
  bool f_intra = false;
  #pragma unroll
  for (int k = 1; k < CPL; ++k) {
    if (idv[k] == run_id) {
      rx += px[k]; ry += py[k]; rz += pz[k];
    } else {
      if (!f_intra) { hx = rx; hy = ry; hz = rz; f_intra = true; }
      else {
        atomicAdd(&out[3 * run_id + 0], rx);
        atomicAdd(&out[3 * run_id + 1], ry);
        atomicAdd(&out[3 * run_id + 2], rz);
      }
      run_id = idv[k];
      rx = px[k]; ry = py[k]; rz = pz[k];
    }
  }
  const int last_id = run_id;

  const int prev_tid = __shfl_up(last_id, 1, 64);
  int fl = (lane == 0 || f_intra || prev_tid != first_id) ? 1 : 0;
  float sx = rx, sy = ry, sz = rz;
  #pragma unroll
  for (int off = 1; off < 64; off <<= 1) {
    const float ox = __shfl_up(sx, off, 64);
    const float oy = __shfl_up(sy, off, 64);
    const float oz = __shfl_up(sz, off, 64);
    const int ofl = __shfl_up(fl, off, 64);
    if (lane >= off && fl == 0) { sx += ox; sy += oy; sz += oz; fl = ofl; }
  }

  const float pSx = __shfl_up(sx, 1, 64);
  const float pSy = __shfl_up(sy, 1, 64);
  const float pSz = __shfl_up(sz, 1, 64);
  if (f_intra) {
    const bool link = (lane > 0) && (prev_tid == first_id);
    atomicAdd(&out[3 * first_id + 0], hx + (link ? pSx : 0.f));
    atomicAdd(&out[3 * first_id + 1], hy + (link ? pSy : 0.f));
    atomicAdd(&out[3 * first_id + 2], hz + (link ? pSz : 0.f));
  }
  const int next_hid = __shfl_down(first_id, 1, 64);
  if (lane == 63 || next_hid != last_id) {
    atomicAdd(&out[3 * last_id + 0], sx);
    atomicAdd(&out[3 * last_id + 1], sy);
    atomicAdd(&out[3 * last_id + 2], sz);
  }
}

__global__ __launch_bounds__(NTHREADS, 4) void integrate_kernel(
    const int* __restrict__ ids, const float* __restrict__ rgb,
    const float* __restrict__ w, float* __restrict__ out, int n_samples) {
  __shared__ char lds[WAVES_PER_BLOCK * 2 * CHUNK_BYTES];  // 40 KB/block
  const int lane = threadIdx.x & 63;
  const int wib = threadIdx.x >> 6;
  char* mybuf = lds + wib * (2 * CHUNK_BYTES);  // wave-private, no barriers

  const long long wave_id = (long long)blockIdx.x * WAVES_PER_BLOCK + wib;
  const long long span0 = wave_id * SPW;
  if (span0 >= (long long)n_samples) return;

  // deferred-flush slots (2 per lane; ids >= 0, so -1 == empty)
  int s0id = -1, s1id = -1;
  float s0x = 0.f, s0y = 0.f, s0z = 0.f, s1x = 0.f, s1y = 0.f, s1z = 0.f;
#define PUSH(pid, pxv, pyv, pzv)                                        \
  do {                                                                  \
    if (s0id < 0)      { s0id = (pid); s0x = (pxv); s0y = (pyv); s0z = (pzv); } \
    else if (s1id < 0) { s1id = (pid); s1x = (pxv); s1y = (pyv); s1z = (pzv); } \
    else {              /* rare overflow -> immediate */                \
      atomicAdd(&out[3 * (pid) + 0], (pxv));                            \
      atomicAdd(&out[3 * (pid) + 1], (pyv));                            \
      atomicAdd(&out[3 * (pid) + 2], (pzv));                            \
    }                                                                   \
  } while (0)

  if (span0 + SPW <= (long long)n_samples) {
    // ---- fast path: LDS-staged depth-2 stream, atomic-free loop ----------
    const char* gid = (const char*)(ids + span0) + lane * 16;
    const char* gw  = (const char*)(w + span0) + lane * 16;
    const char* grg = (const char*)(rgb + 3 * span0) + lane * 16;

#define STAGE(c, b)                                                     \
    do {                                                                \
      const long long o_ = (long long)(c) * (CHUNK * 4);                \
      char* lb_ = mybuf + (b) * CHUNK_BYTES;                            \
      gll16(gid + o_, lb_ + IDS_OFF);                                   \
      gll16(gw + o_, lb_ + W_OFF);                                      \
      gll16(grg + 3 * o_, lb_ + RGB_OFF);                               \
      gll16(grg + 3 * o_ + 1024, lb_ + RGB_OFF + 1024);                 \
      gll16(grg + 3 * o_ + 2048, lb_ + RGB_OFF + 2048);                 \
    } while (0)

    STAGE(0, 0);
    STAGE(1, 1);

    // cross-chunk carry: wave-uniform (broadcast), cid < 0 == invalid
    int cid = -1;
    float cx = 0.f, cy = 0.f, cz = 0.f;

    for (int c = 0; c < CHUNKS; ++c) {
      if (c < CHUNKS - 1) {
        // window holds exactly the 5 stage ops of chunk c+1 (no atomics)
        asm volatile("s_waitcnt vmcnt(5)" ::: "memory");
      } else {
        asm volatile("s_waitcnt vmcnt(0)" ::: "memory");
      }
      const char* lb = mybuf + (c & 1) * CHUNK_BYTES;
      const int4   i4 = *(const int4*)(lb + IDS_OFF + lane * 16);
      const float4 w4 = *(const float4*)(lb + W_OFF + lane * 16);
      const float4 r0 = *(const float4*)(lb + RGB_OFF + lane * 48);
      const float4 r1 = *(const float4*)(lb + RGB_OFF + lane * 48 + 16);
      const float4 r2 = *(const float4*)(lb + RGB_OFF + lane * 48 + 32);

      int idv[CPL] = {i4.x, i4.y, i4.z, i4.w};
      float px[CPL], py[CPL], pz[CPL];
      px[0] = r0.x * w4.x; py[0] = r0.y * w4.x; pz[0] = r0.z * w4.x;
      px[1] = r0.w * w4.y; py[1] = r1.x * w4.y; pz[1] = r1.y * w4.y;
      px[2] = r1.z * w4.z; py[2] = r1.w * w4.z; pz[2] = r2.x * w4.z;
      px[3] = r2.y * w4.w; py[3] = r2.z * w4.w; pz[3] = r2.w * w4.w;

      // per-lane run merge
      const int first_id = idv[0];
      int run_id = first_id;
      float rx = px[0], ry = py[0], rz = pz[0];
      float hx = 0.f, hy = 0.f, hz = 0.f;
      bool f_intra = false;
      #pragma unroll
      for (int k = 1; k < CPL; ++k) {
        if (idv[k] == run_id) {
          rx += px[k]; ry += py[k]; rz += pz[k];
        } else {
          if (!f_intra) { hx = rx; hy = ry; hz = rz; f_intra = true; }
          else          { PUSH(run_id, rx, ry, rz); }  // interior run (rare)
          run_id = idv[k];
          rx = px[k]; ry = py[k]; rz = pz[k];
        }
      }
      const int last_id = run_id;

      // carry injection (lane 0 only; carry is wave-uniform)
      if (lane == 0 && cid >= 0) {
        if (cid == first_id) {
          if (f_intra) { hx += cx; hy += cy; hz += cz; }
          else         { rx += cx; ry += cy; rz += cz; }
        } else {
          PUSH(cid, cx, cy, cz);  // ray ended exactly at chunk boundary
        }
      }

      // cross-lane segmented scan over tail partials
      const int prev_tid = __shfl_up(last_id, 1, 64);
      int fl = (lane == 0 || f_intra || prev_tid != first_id) ? 1 : 0;
      float sx = rx, sy = ry, sz = rz;
      #pragma unroll
      for (int off = 1; off < 64; off <<= 1) {
        const float ox = __shfl_up(sx, off, 64);
        const float oy = __shfl_up(sy, off, 64);
        const float oz = __shfl_up(sz, off, 64);
        const int ofl = __shfl_up(fl, off, 64);
        if (lane >= off && fl == 0) { sx += ox; sy += oy; sz += oz; fl = ofl; }
      }

      // head-run flush (deferred)
      const float pSx = __shfl_up(sx, 1, 64);
      const float pSy = __shfl_up(sy, 1, 64);
      const float pSz = __shfl_up(sz, 1, 64);
      if (f_intra) {
        const bool link = (lane > 0) && (prev_tid == first_id);
        PUSH(first_id, hx + (link ? pSx : 0.f), hy + (link ? pSy : 0.f),
             hz + (link ? pSz : 0.f));
      }

      // tail runs ending strictly inside the wave (deferred);
      // lane 63's tail partial becomes the next chunk's carry
      const int next_hid = __shfl_down(first_id, 1, 64);
      if (lane < 63 && next_hid != last_id) PUSH(last_id, sx, sy, sz);
      cid = __shfl(last_id, 63, 64);
      cx = __shfl(sx, 63, 64);
      cy = __shfl(sy, 63, 64);
      cz = __shfl(sz, 63, 64);

      if (c + 2 < CHUNKS) {
        // LDS reads of this buffer must land before its re-stage
        asm volatile("s_waitcnt lgkmcnt(0)" ::: "memory");
        STAGE(c + 2, c & 1);
      }
    }
#undef STAGE

    // final carry flush
    if (lane == 0 && cid >= 0) PUSH(cid, cx, cy, cz);
  } else {
    // ---- tail path: bounds-checked scalar gather, immediate atomics ------
    const int last = ids[n_samples - 1];
    for (int c = 0; c < CHUNKS; ++c) {
      const long long cb = span0 + (long long)c * CHUNK;
      if (cb >= (long long)n_samples) break;  // wave-uniform
      int idt[CPL]; float wt[CPL], rt[3 * CPL];
      #pragma unroll
      for (int j = 0; j < CPL; ++j) {
        const long long s = cb + (long long)lane * CPL + j;
        if (s < (long long)n_samples) {
          idt[j] = ids[s];
          wt[j] = w[s];
          rt[3 * j + 0] = rgb[3 * s + 0];
          rt[3 * j + 1] = rgb[3 * s + 1];
          rt[3 * j + 2] = rgb[3 * s + 2];
        } else {
          idt[j] = (j == 0) ? last : idt[j - 1];
          wt[j] = 0.f;
          rt[3 * j + 0] = rt[3 * j + 1] = rt[3 * j + 2] = 0.f;
        }
      }
      const int4 i4 = make_int4(idt[0], idt[1], idt[2], idt[3]);
      const float4 w4 = make_float4(wt[0], wt[1], wt[2], wt[3]);
      const float4 r0 = make_float4(rt[0], rt[1], rt[2], rt[3]);
      const float4 r1 = make_float4(rt[4], rt[5], rt[6], rt[7]);
      const float4 r2 = make_float4(rt[8], rt[9], rt[10], rt[11]);
      process_chunk_tailpath(i4, w4, r0, r1, r2, lane, out);
    }
  }

  // drain deferred slots (once per wave)
  if (s0id >= 0) {
    atomicAdd(&out[3 * s0id + 0], s0x);
    atomicAdd(&out[3 * s0id + 1], s0y);
    atomicAdd(&out[3 * s0id + 2], s0z);
  }
  if (s1id >= 0) {
    atomicAdd(&out[3 * s1id + 0], s1x);
    atomicAdd(&out[3 * s1id + 1], s1y);
    atomicAdd(&out[3 * s1id + 2], s1z);
  }
#undef PUSH
}

extern "C" void kernel_launch(void* const* d_in, const int* in_sizes, int n_in,
                              void* d_out, int out_size, void* d_ws, size_t ws_size,
                              hipStream_t stream) {
  const int*   segment_ids = (const int*)d_in[0];
  const float* rgb         = (const float*)d_in[1];
  const float* weights     = (const float*)d_in[2];
  float*       out         = (float*)d_out;

  const int n_samples = in_sizes[0];

  // zero output via memset (capture-safe; harness's own reset uses it)
  hipMemsetAsync(out, 0, out_size, stream);

  long long waves = ((long long)n_samples + SPW - 1) / SPW;
  int blocks = (int)((waves + WAVES_PER_BLOCK - 1) / WAVES_PER_BLOCK);
  integrate_kernel<<<blocks, NTHREADS, 0, stream>>>(
      segment_ids, rgb, weights, out, n_samples);
}

// Round 6
// 194.305 us; speedup vs baseline: 1.0530x; 1.0530x over previous
//
#include <hip/hip_runtime.h>

// out[r] = sum_{s in ray r} w[s] * rgb[s,:]  (segment_ids sorted, fp32)
// Wave-autonomous, barrier-free, LDS-free.
// v6b: m13-copy-bench shape + non-temporal loads (v6 fixed: the nontemporal
// builtin needs clang ext_vector_type, not HIP_vector_type classes).
// Post-mortem v1-v5: five structurally disjoint kernels all pin at 65-70 us /
// ~2.4 TB/s delivered -- MLP depth, occupancy, staging mechanism, and atomics
// all exonerated. Levers under test here:
//   1) cache-allocation policy: single-touch 168 MB stream -> nt loads
//   2) exact m13 shape (6.29 TB/s documented): full-occupancy grid-stride
//      loop, low VGPR, no LDS; 2048 blocks x 256 thr, loads re-issued each
//      iteration
// Chunk body = v1's twice-verified compression + 6-step segmented shuffle
// scan + immediate atomicAdd per run-end (out pre-zeroed via memset).

#define NTHREADS 256
#define WAVES_PER_BLOCK (NTHREADS / 64)
#define CPL 4                 // samples per lane per chunk
#define CHUNK (64 * CPL)      // 256 samples per wave-chunk
#define GRID_BLOCKS 2048      // 8 blocks/CU -> 32 waves/CU resident

typedef float vfloat4 __attribute__((ext_vector_type(4)));
typedef int   vint4   __attribute__((ext_vector_type(4)));

__global__ __launch_bounds__(NTHREADS) void integrate_kernel(
    const int* __restrict__ ids, const float* __restrict__ rgb,
    const float* __restrict__ w, float* __restrict__ out, int n_samples) {
  const int lane = threadIdx.x & 63;
  const long long n_chunks = ((long long)n_samples + CHUNK - 1) / CHUNK;
  const long long wave_id =
      (long long)blockIdx.x * WAVES_PER_BLOCK + (threadIdx.x >> 6);
  const long long n_waves = (long long)gridDim.x * WAVES_PER_BLOCK;

  for (long long ci = wave_id; ci < n_chunks; ci += n_waves) {
    const long long t0 = ci * CHUNK + (long long)lane * CPL;

    int idv[CPL];
    float px[CPL], py[CPL], pz[CPL];
    if (t0 + (CPL - 1) < (long long)n_samples) {  // aligned fast path
      const vint4   id4 = __builtin_nontemporal_load((const vint4*)(ids + t0));
      const vfloat4 w4  = __builtin_nontemporal_load((const vfloat4*)(w + t0));
      const vfloat4* rp = (const vfloat4*)(rgb + 3 * t0);  // 16B-aligned (48B stride)
      const vfloat4 r0 = __builtin_nontemporal_load(rp + 0);
      const vfloat4 r1 = __builtin_nontemporal_load(rp + 1);
      const vfloat4 r2 = __builtin_nontemporal_load(rp + 2);
      idv[0] = id4.x; idv[1] = id4.y; idv[2] = id4.z; idv[3] = id4.w;
      px[0] = r0.x * w4.x; py[0] = r0.y * w4.x; pz[0] = r0.z * w4.x;
      px[1] = r0.w * w4.y; py[1] = r1.x * w4.y; pz[1] = r1.y * w4.y;
      px[2] = r1.z * w4.z; py[2] = r1.w * w4.z; pz[2] = r2.x * w4.z;
      px[3] = r2.y * w4.w; py[3] = r2.z * w4.w; pz[3] = r2.w * w4.w;
    } else {
      // Tail: pads replicate an id with zero contribution; all 64 lanes stay
      // shuffle-active (branch is per-lane, scan below is unconditional).
      const int last = ids[n_samples - 1];
      #pragma unroll
      for (int j = 0; j < CPL; ++j) {
        const long long s = t0 + j;
        if (s < (long long)n_samples) {
          idv[j] = ids[s];
          const float ww = w[s];
          px[j] = rgb[3 * s + 0] * ww;
          py[j] = rgb[3 * s + 1] * ww;
          pz[j] = rgb[3 * s + 2] * ww;
        } else {
          idv[j] = (j == 0) ? last : idv[j - 1];
          px[j] = py[j] = pz[j] = 0.f;
        }
      }
    }

    // ---- per-lane run compression (ids sorted => id0==id3 -> all equal) --
    const int id0 = idv[0], id3 = idv[3];
    const bool f_intra = (id0 != id3);
    const int hl = (idv[1] == id0) ? ((idv[2] == id0) ? ((idv[3] == id0) ? 4 : 3) : 2) : 1;
    const int tl = (idv[2] == id3) ? ((idv[1] == id3) ? ((idv[0] == id3) ? 4 : 3) : 2) : 1;
    float hx = 0.f, hy = 0.f, hz = 0.f, tx = 0.f, ty = 0.f, tz = 0.f;
    #pragma unroll
    for (int j = 0; j < CPL; ++j) {
      if (j < hl)       { hx += px[j]; hy += py[j]; hz += pz[j]; }
      if (j >= CPL - tl){ tx += px[j]; ty += py[j]; tz += pz[j]; }
    }
    // interior complete runs (rare: lane spans >=3 rays) -> flush directly
    {
      const int ilo = hl, ihi = 3 - tl;
      if (ilo <= ihi) {
        if (ilo == ihi) {
          atomicAdd(&out[3 * idv[ilo] + 0], px[ilo]);
          atomicAdd(&out[3 * idv[ilo] + 1], py[ilo]);
          atomicAdd(&out[3 * idv[ilo] + 2], pz[ilo]);
        } else if (idv[ilo] == idv[ihi]) {
          atomicAdd(&out[3 * idv[ilo] + 0], px[ilo] + px[ihi]);
          atomicAdd(&out[3 * idv[ilo] + 1], py[ilo] + py[ihi]);
          atomicAdd(&out[3 * idv[ilo] + 2], pz[ilo] + pz[ihi]);
        } else {
          atomicAdd(&out[3 * idv[ilo] + 0], px[ilo]);
          atomicAdd(&out[3 * idv[ilo] + 1], py[ilo]);
          atomicAdd(&out[3 * idv[ilo] + 2], pz[ilo]);
          atomicAdd(&out[3 * idv[ihi] + 0], px[ihi]);
          atomicAdd(&out[3 * idv[ihi] + 1], py[ihi]);
          atomicAdd(&out[3 * idv[ihi] + 2], pz[ihi]);
        }
      }
    }

    // ---- cross-lane segmented scan over tail partials --------------------
    const int prev_tid = __shfl_up(id3, 1, 64);  // tail id of lane-1
    int fl = (lane == 0 || f_intra || prev_tid != id0) ? 1 : 0;
    float sx = tx, sy = ty, sz = tz;
    #pragma unroll
    for (int off = 1; off < 64; off <<= 1) {
      const float ox = __shfl_up(sx, off, 64);
      const float oy = __shfl_up(sy, off, 64);
      const float oz = __shfl_up(sz, off, 64);
      const int  ofl = __shfl_up(fl, off, 64);
      if (lane >= off && fl == 0) { sx += ox; sy += oy; sz += oz; fl = ofl; }
    }

    // head-run flush: run ending inside this lane at the head prefix
    const float pSx = __shfl_up(sx, 1, 64);
    const float pSy = __shfl_up(sy, 1, 64);
    const float pSz = __shfl_up(sz, 1, 64);
    if (f_intra) {
      const bool link = (lane > 0) && (prev_tid == id0);
      atomicAdd(&out[3 * id0 + 0], hx + (link ? pSx : 0.f));
      atomicAdd(&out[3 * id0 + 1], hy + (link ? pSy : 0.f));
      atomicAdd(&out[3 * id0 + 2], hz + (link ? pSz : 0.f));
    }

    // tail-run flush: last lane of each run within the wave-chunk
    const int next_hid = __shfl_down(id0, 1, 64);  // head id of lane+1
    if (lane == 63 || next_hid != id3) {
      atomicAdd(&out[3 * id3 + 0], sx);
      atomicAdd(&out[3 * id3 + 1], sy);
      atomicAdd(&out[3 * id3 + 2], sz);
    }
  }
}

extern "C" void kernel_launch(void* const* d_in, const int* in_sizes, int n_in,
                              void* d_out, int out_size, void* d_ws, size_t ws_size,
                              hipStream_t stream) {
  const int*   segment_ids = (const int*)d_in[0];
  const float* rgb         = (const float*)d_in[1];
  const float* weights     = (const float*)d_in[2];
  float*       out         = (float*)d_out;

  const int n_samples = in_sizes[0];

  // zero output (all contributions arrive via atomics); capture-safe
  (void)hipMemsetAsync(out, 0, out_size, stream);

  long long n_chunks = ((long long)n_samples + CHUNK - 1) / CHUNK;
  long long need_blocks = (n_chunks + WAVES_PER_BLOCK - 1) / WAVES_PER_BLOCK;
  int blocks = (int)((need_blocks < GRID_BLOCKS) ? need_blocks : GRID_BLOCKS);
  integrate_kernel<<<blocks, NTHREADS, 0, stream>>>(
      segment_ids, rgb, weights, out, n_samples);
}

// Round 7
// 191.393 us; speedup vs baseline: 1.0690x; 1.0152x over previous
//
#include <hip/hip_runtime.h>

// out[r] = sum_{s in ray r} w[s] * rgb[s,:]  (segment_ids sorted, fp32)
// Wave-autonomous, barrier-free, LDS-free.
// v7: CPL=8 discriminator. v6b (nt + m13 grid-stride shape) broke the
// 65-70us plateau -> <58.6us (~2.95 TB/s read-side ~= 95% of m13's read
// rate). Open question: per-CU MSHR wall (no further gain possible) vs
// wave issue-duty wall (burst size still limiting). This kernel doubles
// the per-wave burst: 10 back-to-back dwordx4 loads (10KB in flight/wave),
// half the scan overhead per byte, 2 grid-stride iterations per wave.
// Micro-fix: nt ONLY on ids/w (single-use, perfectly coalesced). rgb uses
// regular loads: its 3 stride-48 instructions share cache lines; nt forced
// up to 3x L2 refetch + 3x MSHR occupancy on 60% of the bytes.
// Chunk body = v5's sequential run merge (generalizes to any CPL) +
// 6-step segmented shuffle scan + immediate atomicAdd per run-end
// (atomics proven cost-free in v5's A/B; out pre-zeroed via memset).

#define NTHREADS 256
#define WAVES_PER_BLOCK (NTHREADS / 64)
#define CPL 8                 // samples per lane per chunk
#define CHUNK (64 * CPL)      // 512 samples per wave-chunk
#define GRID_BLOCKS 2048      // 8 blocks/CU -> full occupancy if VGPR allows

typedef float vfloat4 __attribute__((ext_vector_type(4)));
typedef int   vint4   __attribute__((ext_vector_type(4)));

__global__ __launch_bounds__(NTHREADS) void integrate_kernel(
    const int* __restrict__ ids, const float* __restrict__ rgb,
    const float* __restrict__ w, float* __restrict__ out, int n_samples) {
  const int lane = threadIdx.x & 63;
  const long long n_chunks = ((long long)n_samples + CHUNK - 1) / CHUNK;
  const long long wave_id =
      (long long)blockIdx.x * WAVES_PER_BLOCK + (threadIdx.x >> 6);
  const long long n_waves = (long long)gridDim.x * WAVES_PER_BLOCK;

  for (long long ci = wave_id; ci < n_chunks; ci += n_waves) {
    const long long t0 = ci * CHUNK + (long long)lane * CPL;

    int idv[CPL];
    float px[CPL], py[CPL], pz[CPL];
    if (t0 + (CPL - 1) < (long long)n_samples) {
      // ---- fast path: 10 loads issued back-to-back ----------------------
      const vint4   i0 = __builtin_nontemporal_load((const vint4*)(ids + t0));
      const vint4   i1 = __builtin_nontemporal_load((const vint4*)(ids + t0 + 4));
      const vfloat4 w0 = __builtin_nontemporal_load((const vfloat4*)(w + t0));
      const vfloat4 w1 = __builtin_nontemporal_load((const vfloat4*)(w + t0 + 4));
      const vfloat4* rp = (const vfloat4*)(rgb + 3 * t0);  // 16B-aligned (96B/lane)
      const vfloat4 r0 = rp[0];  // regular (L1-temporal) loads: the 3
      const vfloat4 r1 = rp[1];  // stride-48 instr groups share lines
      const vfloat4 r2 = rp[2];
      const vfloat4 r3 = rp[3];
      const vfloat4 r4 = rp[4];
      const vfloat4 r5 = rp[5];
      idv[0] = i0.x; idv[1] = i0.y; idv[2] = i0.z; idv[3] = i0.w;
      idv[4] = i1.x; idv[5] = i1.y; idv[6] = i1.z; idv[7] = i1.w;
      // sample j uses rgb floats f[3j..3j+2], f[4a+b] = r_a[b]
      px[0] = r0.x * w0.x; py[0] = r0.y * w0.x; pz[0] = r0.z * w0.x;
      px[1] = r0.w * w0.y; py[1] = r1.x * w0.y; pz[1] = r1.y * w0.y;
      px[2] = r1.z * w0.z; py[2] = r1.w * w0.z; pz[2] = r2.x * w0.z;
      px[3] = r2.y * w0.w; py[3] = r2.z * w0.w; pz[3] = r2.w * w0.w;
      px[4] = r3.x * w1.x; py[4] = r3.y * w1.x; pz[4] = r3.z * w1.x;
      px[5] = r3.w * w1.y; py[5] = r4.x * w1.y; pz[5] = r4.y * w1.y;
      px[6] = r4.z * w1.z; py[6] = r4.w * w1.z; pz[6] = r5.x * w1.z;
      px[7] = r5.y * w1.w; py[7] = r5.z * w1.w; pz[7] = r5.w * w1.w;
    } else {
      // ---- tail: pads replicate an id with zero contribution; all 64
      // lanes stay shuffle-active -----------------------------------------
      const int last = ids[n_samples - 1];
      #pragma unroll
      for (int j = 0; j < CPL; ++j) {
        const long long s = t0 + j;
        if (s < (long long)n_samples) {
          idv[j] = ids[s];
          const float ww = w[s];
          px[j] = rgb[3 * s + 0] * ww;
          py[j] = rgb[3 * s + 1] * ww;
          pz[j] = rgb[3 * s + 2] * ww;
        } else {
          idv[j] = (j == 0) ? last : idv[j - 1];
          px[j] = py[j] = pz[j] = 0.f;
        }
      }
    }

    // ---- per-lane sequential run merge (ids sorted within lane) ----------
    const int first_id = idv[0];
    int run_id = first_id;
    float rx = px[0], ry = py[0], rz = pz[0];
    float hx = 0.f, hy = 0.f, hz = 0.f;
    bool f_intra = false;  // true once a run boundary occurred in this lane
    #pragma unroll
    for (int k = 1; k < CPL; ++k) {
      if (idv[k] == run_id) {
        rx += px[k]; ry += py[k]; rz += pz[k];
      } else {
        if (!f_intra) {
          hx = rx; hy = ry; hz = rz; f_intra = true;  // stash head run
        } else {  // interior complete run (rare) -> direct flush
          atomicAdd(&out[3 * run_id + 0], rx);
          atomicAdd(&out[3 * run_id + 1], ry);
          atomicAdd(&out[3 * run_id + 2], rz);
        }
        run_id = idv[k];
        rx = px[k]; ry = py[k]; rz = pz[k];
      }
    }
    const int last_id = run_id;

    // ---- cross-lane segmented scan over tail partials --------------------
    const int prev_tid = __shfl_up(last_id, 1, 64);  // tail id of lane-1
    int fl = (lane == 0 || f_intra || prev_tid != first_id) ? 1 : 0;
    float sx = rx, sy = ry, sz = rz;
    #pragma unroll
    for (int off = 1; off < 64; off <<= 1) {
      const float ox = __shfl_up(sx, off, 64);
      const float oy = __shfl_up(sy, off, 64);
      const float oz = __shfl_up(sz, off, 64);
      const int  ofl = __shfl_up(fl, off, 64);
      if (lane >= off && fl == 0) { sx += ox; sy += oy; sz += oz; fl = ofl; }
    }

    // head-run flush: run ending inside this lane at the head prefix
    const float pSx = __shfl_up(sx, 1, 64);
    const float pSy = __shfl_up(sy, 1, 64);
    const float pSz = __shfl_up(sz, 1, 64);
    if (f_intra) {
      const bool link = (lane > 0) && (prev_tid == first_id);
      atomicAdd(&out[3 * first_id + 0], hx + (link ? pSx : 0.f));
      atomicAdd(&out[3 * first_id + 1], hy + (link ? pSy : 0.f));
      atomicAdd(&out[3 * first_id + 2], hz + (link ? pSz : 0.f));
    }

    // tail-run flush: last lane of each run within the wave-chunk
    const int next_hid = __shfl_down(first_id, 1, 64);  // head id of lane+1
    if (lane == 63 || next_hid != last_id) {
      atomicAdd(&out[3 * last_id + 0], sx);
      atomicAdd(&out[3 * last_id + 1], sy);
      atomicAdd(&out[3 * last_id + 2], sz);
    }
  }
}

extern "C" void kernel_launch(void* const* d_in, const int* in_sizes, int n_in,
                              void* d_out, int out_size, void* d_ws, size_t ws_size,
                              hipStream_t stream) {
  const int*   segment_ids = (const int*)d_in[0];
  const float* rgb         = (const float*)d_in[1];
  const float* weights     = (const float*)d_in[2];
  float*       out         = (float*)d_out;

  const int n_samples = in_sizes[0];

  // zero output (all contributions arrive via atomics); capture-safe
  (void)hipMemsetAsync(out, 0, out_size, stream);

  long long n_chunks = ((long long)n_samples + CHUNK - 1) / CHUNK;
  long long need_blocks = (n_chunks + WAVES_PER_BLOCK - 1) / WAVES_PER_BLOCK;
  int blocks = (int)((need_blocks < GRID_BLOCKS) ? need_blocks : GRID_BLOCKS);
  integrate_kernel<<<blocks, NTHREADS, 0, stream>>>(
      segment_ids, rgb, weights, out, n_samples);
}